// Round 7
// baseline (161.206 us; speedup 1.0000x reference)
//
#include <hip/hip_runtime.h>

#define TT 1024
#define LL 32
#define CHUNK 2
#define NBLK (TT / CHUNK)   // 512 blocks

// ws float offsets
#define ALPHA0_OFF 0                        // 32: alpha0 = Ms[0][BEG][:]
#define PATH_OFF   32                       // 512 path partials
#define P0_OFF     544                      // 512 chunk-product mats (1024 ea)
#define Q1_OFF     (P0_OFF + 512 * 1024)    // 64 mats
#define Q2_OFF     (Q1_OFF + 64 * 1024)     // 8 mats

// All-LDS lse-semiring cell (register-lean, exact max-tree).
__device__ __forceinline__ float lse_cell(const float A[LL][LL + 1],
                                          const float B[LL][LL + 1],
                                          int i, int j) {
  float s[LL];
  #pragma unroll
  for (int k = 0; k < LL; k++) s[k] = A[i][k] + B[k][j];
  float t[16];
  #pragma unroll
  for (int k = 0; k < 16; k++) t[k] = fmaxf(s[k], s[k + 16]);
  #pragma unroll
  for (int st = 8; st >= 1; st >>= 1) {
    #pragma unroll
    for (int k = 0; k < st; k++) t[k] = fmaxf(t[k], t[k + st]);
  }
  const float mx = t[0];
  float a0 = 0.f, a1 = 0.f, a2 = 0.f, a3 = 0.f;
  #pragma unroll
  for (int k = 0; k < LL; k += 4) {
    a0 += __expf(s[k]     - mx);
    a1 += __expf(s[k + 1] - mx);
    a2 += __expf(s[k + 2] - mx);
    a3 += __expf(s[k + 3] - mx);
  }
  return mx + __logf((a0 + a1) + (a2 + a3));
}

// Stage A: 512 blocks x 512 threads (2 blocks/CU). Each block streams 2
// t-slices (1 MiB), R1-style contiguous 1-KiB wave-loads + 5-shfl reduce.
__global__ __launch_bounds__(512, 4) void crf_stageA(
    const float4* __restrict__ X4, const float* __restrict__ w,
    const int* __restrict__ label, float* __restrict__ ws) {
  __shared__ float Ms[CHUNK][LL][LL + 1];
  const int blk = blockIdx.x, tid = threadIdx.x;
  const int l5 = tid & 31;
  const int grp = tid >> 5;               // 0..15
  const float4 w4 = reinterpret_cast<const float4*>(w)[l5];
  const size_t base = (size_t)blk * (CHUNK * 1024) * 32;   // float4 units
  const int t0 = blk * CHUNK;

  #pragma unroll 4
  for (int q = 0; q < 128; q++) {         // 2048 cells / 16 groups
    const int cell = q * 16 + grp;        // wave: lanes0-31 cell, 32-63 cell+1
    float4 xv = X4[base + (size_t)cell * 32 + l5];
    float v = fmaf(xv.x, w4.x, fmaf(xv.y, w4.y, fmaf(xv.z, w4.z, xv.w * w4.w)));
    v += __shfl_xor(v, 16, 32);
    v += __shfl_xor(v,  8, 32);
    v += __shfl_xor(v,  4, 32);
    v += __shfl_xor(v,  2, 32);
    v += __shfl_xor(v,  1, 32);
    if (l5 == 0) {
      const int m = cell >> 10, rem = cell & 1023;
      Ms[m][rem >> 5][rem & 31] = v;
    }
  }
  __syncthreads();

  if (tid == 0) {
    float ps = 0.f;
    #pragma unroll
    for (int m = 0; m < CHUNK; m++) {
      const int t = t0 + m;
      const int lab = label[t];
      const int pv = (t == 0) ? 0 : label[t - 1];   // BEG = 0
      ps += Ms[m][pv][lab];
    }
    ws[PATH_OFF + blk] = ps;
  }
  if (blk == 0 && tid < LL) ws[ALPHA0_OFF + tid] = Ms[0][0][tid];

  // chunk product of 2 mats (1 lse round); blk 0: product excludes Ms[0].
  const int i = tid >> 5, j = tid & 31;   // i in 0..15; also do i+16
  float r0, r1;
  if (blk == 0) {
    r0 = Ms[1][i][j];
    r1 = Ms[1][i + 16][j];
  } else {
    r0 = lse_cell(Ms[0], Ms[1], i, j);
    r1 = lse_cell(Ms[0], Ms[1], i + 16, j);
  }
  ws[P0_OFF + (size_t)blk * 1024 + i * 32 + j] = r0;
  ws[P0_OFF + (size_t)blk * 1024 + (i + 16) * 32 + j] = r1;
}

// comb8: block b -> ordered product of src[8b..8b+7], binary tree (3 rounds).
__global__ __launch_bounds__(1024, 1) void crf_comb8(
    const float* __restrict__ src, float* __restrict__ dst) {
  __shared__ float S[8][LL][LL + 1];
  __shared__ float PQ[4][LL][LL + 1];
  const int blk = blockIdx.x, tid = threadIdx.x;
  const int i = tid >> 5, j = tid & 31;
  #pragma unroll
  for (int m = 0; m < 8; m++)
    S[m][i][j] = src[((size_t)blk * 8 + m) * 1024 + tid];
  __syncthreads();
  #pragma unroll
  for (int q = 0; q < 4; q++)
    PQ[q][i][j] = lse_cell(S[2 * q], S[2 * q + 1], i, j);
  __syncthreads();
  S[0][i][j] = lse_cell(PQ[0], PQ[1], i, j);
  S[1][i][j] = lse_cell(PQ[2], PQ[3], i, j);
  __syncthreads();
  dst[(size_t)blk * 1024 + tid] = lse_cell(S[0], S[1], i, j);
}

// final8: product of 8 mats (depth 3) + logZ + path sum (512) + output.
__global__ __launch_bounds__(1024, 1) void crf_final8(
    const float* __restrict__ ws, float* __restrict__ out) {
  __shared__ float S[8][LL][LL + 1];
  __shared__ float PQ[4][LL][LL + 1];
  __shared__ float redm[16], reds[16], redp[16];
  const int tid = threadIdx.x, i = tid >> 5, j = tid & 31;
  #pragma unroll
  for (int m = 0; m < 8; m++) S[m][i][j] = ws[Q2_OFF + m * 1024 + tid];
  __syncthreads();
  #pragma unroll
  for (int q = 0; q < 4; q++)
    PQ[q][i][j] = lse_cell(S[2 * q], S[2 * q + 1], i, j);
  __syncthreads();
  S[0][i][j] = lse_cell(PQ[0], PQ[1], i, j);
  S[1][i][j] = lse_cell(PQ[2], PQ[3], i, j);
  __syncthreads();
  const float a = lse_cell(S[0], S[1], i, j);
  const float v = ws[ALPHA0_OFF + i] + a;

  float mx = v;
  #pragma unroll
  for (int o = 32; o >= 1; o >>= 1) mx = fmaxf(mx, __shfl_xor(mx, o));
  const int wv = tid >> 6, lane = tid & 63;
  if (lane == 0) redm[wv] = mx;
  __syncthreads();
  float mb = redm[0];
  #pragma unroll
  for (int q = 1; q < 16; q++) mb = fmaxf(mb, redm[q]);
  float e = __expf(v - mb);
  float p = (tid < 512) ? ws[PATH_OFF + tid] : 0.f;
  #pragma unroll
  for (int o = 32; o >= 1; o >>= 1) {
    e += __shfl_xor(e, o);
    p += __shfl_xor(p, o);
  }
  if (lane == 0) { reds[wv] = e; redp[wv] = p; }
  __syncthreads();
  if (tid == 0) {
    float s = 0.f, ps = 0.f;
    for (int q = 0; q < 16; q++) { s += reds[q]; ps += redp[q]; }
    out[0] = -ps + (mb + __logf(s));
  }
}

extern "C" void kernel_launch(void* const* d_in, const int* in_sizes, int n_in,
                              void* d_out, int out_size, void* d_ws, size_t ws_size,
                              hipStream_t stream) {
  const float4* X4 = (const float4*)d_in[0];
  const float* w = (const float*)d_in[1];
  const int* label = (const int*)d_in[2];
  float* out = (float*)d_out;
  float* ws = (float*)d_ws;

  crf_stageA<<<NBLK, 512, 0, stream>>>(X4, w, label, ws);
  crf_comb8<<<64, 1024, 0, stream>>>(ws + P0_OFF, ws + Q1_OFF);   // 512 -> 64
  crf_comb8<<<8, 1024, 0, stream>>>(ws + Q1_OFF, ws + Q2_OFF);    //  64 -> 8
  crf_final8<<<1, 1024, 0, stream>>>(ws, out);
}

// Round 8
// 156.225 us; speedup vs baseline: 1.0319x; 1.0319x over previous
//
#include <hip/hip_runtime.h>

#define LL 32
#define TT 1024

// ws float offsets
#define MS_OFF 0                          // 1024 mats: Ms[t][i][j] compact
#define Q1_OFF (MS_OFF + 1024 * 1024)     // 128 mats
#define Q2_OFF (Q1_OFF + 128 * 1024)      // 16 mats
#define Q3_OFF (Q2_OFF + 16 * 1024)       // 2 mats

// All-LDS lse-semiring cell (register-lean, exact max-tree). R6-proven.
__device__ __forceinline__ float lse_cell(const float A[LL][LL + 1],
                                          const float B[LL][LL + 1],
                                          int i, int j) {
  float s[LL];
  #pragma unroll
  for (int k = 0; k < LL; k++) s[k] = A[i][k] + B[k][j];
  float t[16];
  #pragma unroll
  for (int k = 0; k < 16; k++) t[k] = fmaxf(s[k], s[k + 16]);
  #pragma unroll
  for (int st = 8; st >= 1; st >>= 1) {
    #pragma unroll
    for (int k = 0; k < st; k++) t[k] = fmaxf(t[k], t[k + st]);
  }
  const float mx = t[0];
  float a0 = 0.f, a1 = 0.f, a2 = 0.f, a3 = 0.f;
  #pragma unroll
  for (int k = 0; k < LL; k += 4) {
    a0 += __expf(s[k]     - mx);
    a1 += __expf(s[k + 1] - mx);
    a2 += __expf(s[k + 2] - mx);
    a3 += __expf(s[k + 3] - mx);
  }
  return mx + __logf((a0 + a1) + (a2 + a3));
}

// K1: pure streaming GEMV via global_load_lds DMA.
// 1024 blocks x 256 threads; block b computes matrix b (1024 cells, 512 KiB X).
// Tile = 32 cells (16 KiB LDS): DMA in, dot out of LDS, 3-shfl reduce.
__global__ __launch_bounds__(256, 6) void crf_gemv(
    const float* __restrict__ X, const float* __restrict__ w,
    float* __restrict__ ms) {
  __shared__ float buf[4096];              // 16 KiB tile
  const int tid = threadIdx.x;
  const int lane = tid & 63, wid = tid >> 6;   // 4 waves
  const int c = tid >> 3, sub = tid & 7;       // 8 threads per cell
  float4 wr[4];
  #pragma unroll
  for (int s = 0; s < 4; s++)
    wr[s] = reinterpret_cast<const float4*>(w)[sub * 4 + s];   // k = sub*16+s*4..
  const char* xb = (const char*)X + (size_t)blockIdx.x * 524288;
  float* msb = ms + (size_t)blockIdx.x * 1024;

  for (int tile = 0; tile < 32; tile++) {
    const char* src = xb + tile * 16384 + wid * 4096 + lane * 16;
    #pragma unroll
    for (int u = 0; u < 4; u++) {
      __builtin_amdgcn_global_load_lds(
          (const __attribute__((address_space(1))) void*)(src + u * 1024),
          (__attribute__((address_space(3))) void*)&buf[(wid * 4 + u) * 256],
          16, 0, 0);
    }
    __syncthreads();                       // vmcnt drain + publish tile
    const float4* bf = reinterpret_cast<const float4*>(buf);
    float acc = 0.f;
    #pragma unroll
    for (int s = 0; s < 4; s++) {
      const float4 xv = bf[c * 32 + sub * 4 + s];
      acc = fmaf(xv.x, wr[s].x,
            fmaf(xv.y, wr[s].y, fmaf(xv.z, wr[s].z, fmaf(xv.w, wr[s].w, acc))));
    }
    acc += __shfl_xor(acc, 1);
    acc += __shfl_xor(acc, 2);
    acc += __shfl_xor(acc, 4);
    if (sub == 0) msb[tile * 32 + c] = acc;
    __syncthreads();                       // reads done before next DMA overwrite
  }
}

// comb8: block b -> ordered product of src[8b..8b+7], binary tree (3 rounds).
// skip0: block 0 replaces slot 0 with the exact lse-identity (Ms[0] -> alpha0).
__global__ __launch_bounds__(1024, 1) void crf_comb8(
    const float* __restrict__ src, float* __restrict__ dst, int skip0) {
  __shared__ float S[8][LL][LL + 1];
  __shared__ float PQ[4][LL][LL + 1];
  const int blk = blockIdx.x, tid = threadIdx.x;
  const int i = tid >> 5, j = tid & 31;
  #pragma unroll
  for (int m = 0; m < 8; m++) {
    float v = src[((size_t)blk * 8 + m) * 1024 + tid];
    if (skip0 && blk == 0 && m == 0) v = (i == j) ? 0.f : -1e30f;
    S[m][i][j] = v;
  }
  __syncthreads();
  #pragma unroll
  for (int q = 0; q < 4; q++)
    PQ[q][i][j] = lse_cell(S[2 * q], S[2 * q + 1], i, j);
  __syncthreads();
  S[0][i][j] = lse_cell(PQ[0], PQ[1], i, j);
  S[1][i][j] = lse_cell(PQ[2], PQ[3], i, j);
  __syncthreads();
  dst[(size_t)blk * 1024 + tid] = lse_cell(S[0], S[1], i, j);
}

// final2: product of the last 2 mats + logZ + fully-parallel path gather.
__global__ __launch_bounds__(1024, 1) void crf_final2(
    const float* __restrict__ ws, const int* __restrict__ label,
    float* __restrict__ out) {
  __shared__ float S[2][LL][LL + 1];
  __shared__ float redm[16], reds[16], redp[16];
  const int tid = threadIdx.x, i = tid >> 5, j = tid & 31;
  #pragma unroll
  for (int m = 0; m < 2; m++) S[m][i][j] = ws[Q3_OFF + m * 1024 + tid];
  __syncthreads();
  const float a = lse_cell(S[0], S[1], i, j);
  const float v = ws[MS_OFF + i] + a;      // alpha0[i] = Ms[0][0][i]
  const int lab = label[tid];
  const int pv = (tid == 0) ? 0 : label[tid - 1];   // BEG = 0
  const float pval = ws[MS_OFF + (size_t)tid * 1024 + pv * 32 + lab];

  float mx = v;
  #pragma unroll
  for (int o = 32; o >= 1; o >>= 1) mx = fmaxf(mx, __shfl_xor(mx, o));
  const int wv = tid >> 6, lane = tid & 63;
  if (lane == 0) redm[wv] = mx;
  __syncthreads();
  float mb = redm[0];
  #pragma unroll
  for (int q = 1; q < 16; q++) mb = fmaxf(mb, redm[q]);
  float e = __expf(v - mb);
  float p = pval;
  #pragma unroll
  for (int o = 32; o >= 1; o >>= 1) {
    e += __shfl_xor(e, o);
    p += __shfl_xor(p, o);
  }
  if (lane == 0) { reds[wv] = e; redp[wv] = p; }
  __syncthreads();
  if (tid == 0) {
    float s = 0.f, ps = 0.f;
    for (int q = 0; q < 16; q++) { s += reds[q]; ps += redp[q]; }
    out[0] = -ps + (mb + __logf(s));
  }
}

extern "C" void kernel_launch(void* const* d_in, const int* in_sizes, int n_in,
                              void* d_out, int out_size, void* d_ws, size_t ws_size,
                              hipStream_t stream) {
  const float* X = (const float*)d_in[0];
  const float* w = (const float*)d_in[1];
  const int* label = (const int*)d_in[2];
  float* out = (float*)d_out;
  float* ws = (float*)d_ws;

  crf_gemv<<<1024, 256, 0, stream>>>(X, w, ws + MS_OFF);
  crf_comb8<<<128, 1024, 0, stream>>>(ws + MS_OFF, ws + Q1_OFF, 1);  // 1024->128
  crf_comb8<<<16, 1024, 0, stream>>>(ws + Q1_OFF, ws + Q2_OFF, 0);   //  128->16
  crf_comb8<<<2, 1024, 0, stream>>>(ws + Q2_OFF, ws + Q3_OFF, 0);    //   16->2
  crf_final2<<<1, 1024, 0, stream>>>(ws, label, out);
}